// Round 1
// baseline (5108.964 us; speedup 1.0000x reference)
//
#include <hip/hip_runtime.h>
#include <math.h>

// QuantumMambaSSMCore: 10-qubit state-vector scan, B=128, S=512.
// Design notes:
//  - 1 block per batch element (hard parallelism cap: state can't span blocks).
//  - 512 threads/block; thread owns amplitudes at slots j0=2*tid, j1=2*tid+1.
//  - CNOTs folded into compile-time GF(2) basis masks (v = pair XOR offset,
//    m = physical-bit parity mask). Zero data movement for all 58 CNOTs.
//  - QSVT RZ gates are diagonal -> register-only. Variational RX*RY*RZ fused
//    into one constant complex 2x2 per wire (computed once per block).
//  - Pair gates: write own float4 -> barrier -> read partner float4 from
//    double-buffered LDS (race-free with 1 barrier/gate).
//  - <Z_w> via 2 Walsh butterflies over lanes (12 shuffles/step total).

#define PIF 3.14159265358979323846f

constexpr int NQ   = 10;
constexpr int SEQ  = 512;
constexpr int NB   = 128;
constexpr int NTHR = 512;

struct CTbl {
  int vh[NQ], mh[NQ];          // phase A: RY(h[i])
  int vz[4][NQ], mz[4][NQ];    // phase B: RZ(pc[d]*theta[i]*PI)  (diagonal)
  int vu[2][NQ], mu[2][NQ];    // phase C: fused SU(2) from circuit_params
  int vf[NQ], mf[NQ];          // phase D: RY(x[i]*theta[i])
  int zm[NQ];                  // measurement parity masks
};

constexpr CTbl build_tbl() {
  CTbl t{};
  unsigned mrow[NQ], vcol[NQ];
  for (int b = 0; b < NQ; ++b) { mrow[b] = 1u << b; vcol[b] = 1u << b; }
  // wire i <-> bit (9-i) of the flattened index (axis 1 of reshape = MSB).
  for (int i = 0; i < NQ; ++i) { t.vh[i] = (int)vcol[9 - i]; t.mh[i] = (int)mrow[9 - i]; }
  for (int d = 0; d < 4; ++d) {
    for (int i = 0; i < NQ; ++i) { t.vz[d][i] = (int)vcol[9 - i]; t.mz[d][i] = (int)mrow[9 - i]; }
    for (int i = 0; i < NQ - 1; ++i) {           // CNOT(control=i, target=i+1)
      int bc = 9 - i, bt = 8 - i;
      mrow[bt] ^= mrow[bc];
      vcol[bc] ^= vcol[bt];
    }
    { int bc = 0, bt = 9;                        // CNOT(control=9, target=0)
      mrow[bt] ^= mrow[bc];
      vcol[bc] ^= vcol[bt]; }
  }
  for (int l = 0; l < 2; ++l) {
    for (int i = 0; i < NQ; ++i) { t.vu[l][i] = (int)vcol[9 - i]; t.mu[l][i] = (int)mrow[9 - i]; }
    for (int i = 0; i < NQ - 1; ++i) {
      int bc = 9 - i, bt = 8 - i;
      mrow[bt] ^= mrow[bc];
      vcol[bc] ^= vcol[bt];
    }
  }
  for (int i = 0; i < NQ; ++i) { t.vf[i] = (int)vcol[9 - i]; t.mf[i] = (int)mrow[9 - i]; }
  for (int i = 0; i < NQ; ++i) t.zm[i] = (int)mrow[9 - i];
  return t;
}

constexpr CTbl CT = build_tbl();

__global__ __launch_bounds__(NTHR) void qmamba_kernel(
    const float* __restrict__ angles, const float* __restrict__ Wx,
    const float* __restrict__ Wdt, const float* __restrict__ bdt,
    const float* __restrict__ pc, const float* __restrict__ cp,
    const float* __restrict__ Dg, float* __restrict__ out)
{
  __shared__ __align__(16) float2 buf[2][1024];   // double-buffered state, 16 KB
  __shared__ float2 uu[20][4];                    // fused U: u00,u01,u10,u11
  __shared__ float hc[NQ], hsn[NQ];               // cos/sin of h/2
  __shared__ float zc[4][NQ], zsn[4][NQ];         // cos/sin of RZ half-angles
  __shared__ float fc[NQ], fsn[NQ];               // cos/sin of final-RY half-angles
  __shared__ float Cs[NQ], av[NQ], Dl[NQ], hb[NQ];
  __shared__ float part[NQ * 8];

  const int tid  = threadIdx.x;
  const int b    = blockIdx.x;
  const int lane = tid & 63;
  const int wid  = tid >> 6;

  // ---- once per launch: fused variational unitaries U = RZ(g)*RY(be)*RX(al)
  if (tid < 20) {
    int k = tid * 3;
    float al = 0.5f * cp[k], be = 0.5f * cp[k + 1], ga = 0.5f * cp[k + 2];
    float ca = __cosf(al), sa = __sinf(al);
    float cb = __cosf(be), sb = __sinf(be);
    float cg = __cosf(ga), sg = __sinf(ga);
    // M = RY*RX:
    float2 M00 = make_float2(cb * ca,  sb * sa);
    float2 M01 = make_float2(-sb * ca, -cb * sa);
    float2 M10 = make_float2(sb * ca,  -cb * sa);
    float2 M11 = make_float2(cb * ca,  -sb * sa);
    float2 e0 = make_float2(cg, -sg), e1 = make_float2(cg, sg); // RZ phases
    auto cm = [](float2 a, float2 c) {
      return make_float2(a.x * c.x - a.y * c.y, a.x * c.y + a.y * c.x);
    };
    uu[tid][0] = cm(M00, e0);
    uu[tid][1] = cm(M01, e0);
    uu[tid][2] = cm(M10, e1);
    uu[tid][3] = cm(M11, e1);
  }
  if (tid < NQ) { hb[tid] = 0.0f; Dl[tid] = Dg[tid]; }

  int cb_ = 0;
  float2 r0, r1;

  for (int t = 0; t < SEQ; ++t) {
    __syncthreads();  // hb / part / tables from previous iteration settled

    // ---- per-step preamble: theta, C, trig tables (threads 0..9)
    if (tid < NQ) {
      const int w = tid;
      const float* ar = angles + (size_t)(b * SEQ + t) * NQ;
      float a[NQ];
#pragma unroll
      for (int n = 0; n < NQ; ++n) a[n] = ar[n];
      float dtr[5];
#pragma unroll
      for (int r = 0; r < 5; ++r) {
        float acc = 0.f;
#pragma unroll
        for (int n = 0; n < NQ; ++n) acc += a[n] * Wx[r * NQ + n];
        dtr[r] = acc;
      }
      float Cv = 0.f;
#pragma unroll
      for (int n = 0; n < NQ; ++n) Cv += a[n] * Wx[(15 + w) * NQ + n];
      float lin = bdt[w];
#pragma unroll
      for (int r = 0; r < 5; ++r) lin += dtr[r] * Wdt[w * 5 + r];
      float sp = lin > 0.f ? lin + log1pf(__expf(-lin)) : log1pf(__expf(lin));
      float th = tanhf(sp) * PIF;                 // dt_angles
      Cs[w] = Cv; av[w] = a[w];
      float hh = 0.5f * hb[w];
      hc[w] = __cosf(hh); hsn[w] = __sinf(hh);
#pragma unroll
      for (int d = 0; d < 4; ++d) {
        float ang = 0.5f * pc[d] * th * PIF;      // RZ(pc[d]*dt_angles*PI)
        zc[d][w] = __cosf(ang); zsn[d][w] = __sinf(ang);
      }
      float fa = 0.5f * a[w] * th;                // RY(x*dt_angles)
      fc[w] = __cosf(fa); fsn[w] = __sinf(fa);
    }
    __syncthreads();

    // ---- init |0...0> (physical p=0 <-> slot 0 since phi is linear)
    r0 = make_float2(tid == 0 ? 1.f : 0.f, 0.f);
    r1 = make_float2(0.f, 0.f);

    auto pair_fetch = [&](int v, float2& p0, float2& p1) {
      float4* bp = (float4*)buf[cb_];
      bp[tid] = make_float4(r0.x, r0.y, r1.x, r1.y);
      __syncthreads();
      float4 P = bp[((2 * tid) ^ v) >> 1];
      cb_ ^= 1;
      if (v & 1) { p0 = make_float2(P.z, P.w); p1 = make_float2(P.x, P.y); }
      else       { p0 = make_float2(P.x, P.y); p1 = make_float2(P.z, P.w); }
    };

    auto gate_ry = [&](int v, int m, float cc, float ssv) {
      float2 p0, p1;
      pair_fetch(v, p0, p1);
      int par0 = __popc((2 * tid) & m) & 1;
      float ss0 = par0 ? ssv : -ssv;          // bit0: c*own - s*partner
      float ss1 = (m & 1) ? -ss0 : ss0;
      r0.x = cc * r0.x + ss0 * p0.x; r0.y = cc * r0.y + ss0 * p0.y;
      r1.x = cc * r1.x + ss1 * p1.x; r1.y = cc * r1.y + ss1 * p1.y;
    };

    auto gate_rz = [&](int m, float cc, float ssv) {     // diag(e^{-it/2}, e^{+it/2})
      int par0 = __popc((2 * tid) & m) & 1;
      float ss0 = par0 ? -ssv : ssv;
      float ss1 = (m & 1) ? -ss0 : ss0;
      float nre = cc * r0.x + ss0 * r0.y;
      float nim = cc * r0.y - ss0 * r0.x;
      r0.x = nre; r0.y = nim;
      nre = cc * r1.x + ss1 * r1.y;
      nim = cc * r1.y - ss1 * r1.x;
      r1.x = nre; r1.y = nim;
    };

    auto gate_u = [&](int v, int m, int g) {
      float2 p0, p1;
      pair_fetch(v, p0, p1);
      float2 u00 = uu[g][0], u01 = uu[g][1], u10 = uu[g][2], u11 = uu[g][3];
      int par0 = __popc((2 * tid) & m) & 1;
      int par1 = par0 ^ (m & 1);
      float2 A0 = par0 ? u11 : u00, B0 = par0 ? u10 : u01;
      float2 A1 = par1 ? u11 : u00, B1 = par1 ? u10 : u01;
      float2 n0, n1;
      n0.x = A0.x * r0.x - A0.y * r0.y + B0.x * p0.x - B0.y * p0.y;
      n0.y = A0.x * r0.y + A0.y * r0.x + B0.x * p0.y + B0.y * p0.x;
      n1.x = A1.x * r1.x - A1.y * r1.y + B1.x * p1.x - B1.y * p1.y;
      n1.y = A1.x * r1.y + A1.y * r1.x + B1.x * p1.y + B1.y * p1.x;
      r0 = n0; r1 = n1;
    };

    // Phase A: RY(h)
#pragma unroll
    for (int i = 0; i < NQ; ++i) gate_ry(CT.vh[i], CT.mh[i], hc[i], hsn[i]);
    // Phase B: QSVT RZ layers (diagonal, no comm) — CNOTs folded into masks
#pragma unroll
    for (int d = 0; d < 4; ++d) {
#pragma unroll
      for (int i = 0; i < NQ; ++i) gate_rz(CT.mz[d][i], zc[d][i], zsn[d][i]);
    }
    // Phase C: fused variational SU(2) layers
#pragma unroll
    for (int l = 0; l < 2; ++l) {
#pragma unroll
      for (int i = 0; i < NQ; ++i) gate_u(CT.vu[l][i], CT.mu[l][i], l * NQ + i);
    }
    // Phase D: RY(x*dt)
#pragma unroll
    for (int i = 0; i < NQ; ++i) gate_ry(CT.vf[i], CT.mf[i], fc[i], fsn[i]);

    // ---- measurement: z_w = sum_j p_j * (-1)^{popc(j & zm[w])}
    float p0 = r0.x * r0.x + r0.y * r0.y;
    float p1 = r1.x * r1.x + r1.y * r1.y;
    // slot j = (wid<<7)|(lane<<1)|r : handle r-bit by two Walsh inputs
    float spl = p0 + p1, smi = p0 - p1;
#pragma unroll
    for (int k = 0; k < 6; ++k) {
      float o1 = __shfl_xor(spl, 1 << k, 64);
      float o2 = __shfl_xor(smi, 1 << k, 64);
      spl = ((lane >> k) & 1) ? (o1 - spl) : (spl + o1);
      smi = ((lane >> k) & 1) ? (o2 - smi) : (smi + o2);
    }
    // after butterfly: lane L holds sum_l x_l * (-1)^{popc(l & L)}
#pragma unroll
    for (int w = 0; w < NQ; ++w) {
      const int m  = CT.zm[w];
      const int mL = (m >> 1) & 63;
      float val = (m & 1) ? smi : spl;
      if (lane == mL) {
        float sgn = (__popc(wid & (m >> 7)) & 1) ? -1.f : 1.f;
        part[w * 8 + wid] = sgn * val;
      }
    }
    __syncthreads();
    if (tid < NQ) {
      float z = 0.f;
#pragma unroll
      for (int k = 0; k < 8; ++k) z += part[tid * 8 + k];
      out[(size_t)(b * SEQ + t) * NQ + tid] = Cs[tid] * z + Dl[tid] * av[tid];
      hb[tid] = z;   // h for next step
    }
  }
}

extern "C" void kernel_launch(void* const* d_in, const int* in_sizes, int n_in,
                              void* d_out, int out_size, void* d_ws, size_t ws_size,
                              hipStream_t stream) {
  (void)in_sizes; (void)n_in; (void)d_ws; (void)ws_size; (void)out_size;
  const float* angles = (const float*)d_in[0];
  const float* Wx     = (const float*)d_in[1];
  const float* Wdt    = (const float*)d_in[2];
  const float* bdt    = (const float*)d_in[3];
  const float* pc     = (const float*)d_in[4];
  const float* cp     = (const float*)d_in[5];
  const float* Dg     = (const float*)d_in[6];
  float* out = (float*)d_out;
  hipLaunchKernelGGL(qmamba_kernel, dim3(NB), dim3(NTHR), 0, stream,
                     angles, Wx, Wdt, bdt, pc, cp, Dg, out);
}